// Round 2
// baseline (1583.230 us; speedup 1.0000x reference)
//
#include <hip/hip_runtime.h>

#define NQ 4096
#define NPT 1024
#define CAP 16

typedef float vf2 __attribute__((ext_vector_type(2)));
typedef unsigned long long ull;

struct KnnSm { float4 pts[2048]; unsigned long long qbuf[CAP * 256]; };   // 64 KB
struct FpsSm { float4 pts[NQ]; ull slots[2][2][4]; };                     // 64 KB + 128 B
struct GemmSm {
  float fnb[16][132]; float fqb[16][8]; float Alds[128][8]; float Dlds[128][8];
  int last;
};
union FusedSm { KnnSm k; FpsSm f; GemmSm g; };

struct Ctl { int f8_done, knn_done, fps_done, stats_done, fin_done, pad0, pad1, pad2;
             int fps_prog[8]; };   // 64 B, zeroed by memset each launch

__device__ inline void spin_ge(int* p, int target) {
  while (__hip_atomic_load(p, __ATOMIC_RELAXED, __HIP_MEMORY_SCOPE_AGENT) < target)
    __builtin_amdgcn_s_sleep(16);
}
__device__ inline void release_inc(int* p) {
  __threadfence();   // make this block's global writes visible device-wide
  __hip_atomic_fetch_add(p, 1, __ATOMIC_RELAXED, __HIP_MEMORY_SCOPE_AGENT);
}

// 64-bit lexicographic max across the wave via DPP; result broadcast to all
// lanes of each row pair by the final bcast steps (lane63 has full-wave max,
// bcast:31 pushes row0's max into row1 etc. — net: lane63 exact; we only use
// the value after the full 6-step chain on every lane uniformly).
#define DPP64S(key, CTRL)                                                      \
  {                                                                            \
    unsigned slo = (unsigned)__builtin_amdgcn_update_dpp(                      \
        0, (int)(unsigned)(key), CTRL, 0xF, 0xF, true);                        \
    unsigned shi = (unsigned)__builtin_amdgcn_update_dpp(                      \
        0, (int)(unsigned)((key) >> 32), CTRL, 0xF, 0xF, true);                \
    ull sk = ((ull)shi << 32) | slo;                                           \
    key = (sk > key) ? sk : key;                                               \
  }
#define DPP6(key)                                                              \
  DPP64S(key, 0x111) DPP64S(key, 0x112) DPP64S(key, 0x114) DPP64S(key, 0x118)  \
  DPP64S(key, 0x142) DPP64S(key, 0x143)

// fused min-update + 16-slot argmax tree + monotone key build.
// Bitwise-identical distance math to the verified kernel: vf2 subs/muls,
// (a+b)+c adds, fminf — no fma (fp contract off in caller scope).
#define FPS_STEP(PX, PY, PZ, DD, WX, WY, WZ, KEYVAR)                           \
  {                                                                            \
    vf2 wxv = vf2{WX, WX}, wyv = vf2{WY, WY}, wzv = vf2{WZ, WZ};               \
    float tvv[8]; int tss[8];                                                  \
    _Pragma("unroll")                                                          \
    for (int p = 0; p < 8; p++) {                                              \
      vf2 dx = PX[p] - wxv, dy = PY[p] - wyv, dz = PZ[p] - wzv;                \
      vf2 a = dx * dx, bq = dy * dy, cq = dz * dz;                             \
      vf2 d = (a + bq) + cq;                                                   \
      float nx = fminf(DD[p].x, d.x);                                          \
      float ny = fminf(DD[p].y, d.y);                                          \
      DD[p].x = nx; DD[p].y = ny;                                              \
      bool g = ny > nx;                                                        \
      tvv[p] = g ? ny : nx;                                                    \
      tss[p] = g ? (2 * p + 1) : (2 * p);                                      \
    }                                                                          \
    _Pragma("unroll")                                                          \
    for (int s = 0; s < 4; s++) {                                              \
      bool g = tvv[2 * s + 1] > tvv[2 * s];                                    \
      tvv[s] = g ? tvv[2 * s + 1] : tvv[2 * s];                                \
      tss[s] = g ? tss[2 * s + 1] : tss[2 * s];                                \
    }                                                                          \
    bool g0 = tvv[1] > tvv[0];                                                 \
    float u0 = g0 ? tvv[1] : tvv[0]; int s0p = g0 ? tss[1] : tss[0];           \
    bool g1 = tvv[3] > tvv[2];                                                 \
    float u1 = g1 ? tvv[3] : tvv[2]; int s1p = g1 ? tss[3] : tss[2];           \
    bool gf = u1 > u0;                                                         \
    float mv = gf ? u1 : u0; int ms = gf ? s1p : s0p;                          \
    KEYVAR = itbase | ((ull)__float_as_uint(mv) << 12) |                       \
             (ull)(invbase - ((unsigned)ms << 8));                             \
  }

__global__ __launch_bounds__(256, 2) void mega_kernel(
    const float* __restrict__ x, const float* __restrict__ f,
    const float* __restrict__ w_in, const float* __restrict__ b_in,
    const float* __restrict__ w1, const float* __restrict__ gnw,
    const float* __restrict__ gnb, float* __restrict__ f8t,
    int* __restrict__ knn, int* __restrict__ fps_g, double* __restrict__ stats,
    float* __restrict__ musd, Ctl* __restrict__ ctl, float* __restrict__ out) {
  __shared__ FusedSm sm;
  int tid = threadIdx.x;
  int bk = blockIdx.x;

  if (bk < 4) {
    // ===== FPS: two interleaved batches per block (latency-hiding pair) =====
    // Batch A = bk (coords in LDS float4), batch B = bk+4 (coords via L2).
    // Monotone keys [it:10|dist:32|inv:12] in parity-double-buffered slots;
    // poll condition: slot >= it<<44; max of 4 slots IS the winner key.
#pragma clang fp contract(off)
    int bA = bk, bB = bk + 4;
    const float* xa = x + (size_t)bA * 3 * NQ;
    const float* xg = x + (size_t)bB * 3 * NQ;
    vf2 pxA[8], pyA[8], pzA[8], dA[8];
    vf2 pxB[8], pyB[8], pzB[8], dB[8];
#pragma unroll
    for (int p = 0; p < 8; p++) {
      int i0 = (p << 9) + tid, i1 = i0 + 256;
      float X0 = xa[i0], Y0 = xa[NQ + i0], Z0 = xa[2 * NQ + i0];
      float X1 = xa[i1], Y1 = xa[NQ + i1], Z1 = xa[2 * NQ + i1];
      pxA[p] = vf2{X0, X1}; pyA[p] = vf2{Y0, Y1}; pzA[p] = vf2{Z0, Z1};
      sm.f.pts[i0] = make_float4(X0, Y0, Z0, 0.f);
      sm.f.pts[i1] = make_float4(X1, Y1, Z1, 0.f);
      dA[p] = vf2{3.4e38f, 3.4e38f};     // sentinel: fminf(BIG, d_p0)==d_p0
      float U0 = xg[i0], V0 = xg[NQ + i0], W0 = xg[2 * NQ + i0];
      float U1 = xg[i1], V1 = xg[NQ + i1], W1 = xg[2 * NQ + i1];
      pxB[p] = vf2{U0, U1}; pyB[p] = vf2{V0, V1}; pzB[p] = vf2{W0, W1};
      dB[p] = vf2{3.4e38f, 3.4e38f};
    }
    float wxA = xa[0], wyA = xa[NQ], wzA = xa[2 * NQ];
    float wxB = xg[0], wyB = xg[NQ], wzB = xg[2 * NQ];
    if (tid == 0) { fps_g[bA * NPT] = 0; fps_g[bB * NPT] = 0; }
    if (tid < 16) sm.f.slots[tid >> 3][(tid >> 2) & 1][tid & 3] = 0ull;
    __syncthreads();
    unsigned invbase = (unsigned)(4095 - tid);
    for (int it = 1; it < NPT; it++) {
      ull itbase = (ull)(unsigned)it << 44;
      int par = it & 1;
      ull keyA, keyB;
      FPS_STEP(pxA, pyA, pzA, dA, wxA, wyA, wzA, keyA)
      FPS_STEP(pxB, pyB, pzB, dB, wxB, wyB, wzB, keyB)
      DPP6(keyA)
      DPP6(keyB)
      if ((tid & 63) == 63) {
        __hip_atomic_store(&sm.f.slots[0][par][tid >> 6], keyA,
                           __ATOMIC_RELAXED, __HIP_MEMORY_SCOPE_WORKGROUP);
        __hip_atomic_store(&sm.f.slots[1][par][tid >> 6], keyB,
                           __ATOMIC_RELAXED, __HIP_MEMORY_SCOPE_WORKGROUP);
      }
      // ---- poll A ----------------------------------------------------------
      ull a0, a1, a2, a3;
      for (;;) {
        a0 = __hip_atomic_load(&sm.f.slots[0][par][0], __ATOMIC_RELAXED, __HIP_MEMORY_SCOPE_WORKGROUP);
        a1 = __hip_atomic_load(&sm.f.slots[0][par][1], __ATOMIC_RELAXED, __HIP_MEMORY_SCOPE_WORKGROUP);
        a2 = __hip_atomic_load(&sm.f.slots[0][par][2], __ATOMIC_RELAXED, __HIP_MEMORY_SCOPE_WORKGROUP);
        a3 = __hip_atomic_load(&sm.f.slots[0][par][3], __ATOMIC_RELAXED, __HIP_MEMORY_SCOPE_WORKGROUP);
        if (a0 >= itbase && a1 >= itbase && a2 >= itbase && a3 >= itbase) break;
      }
      ull m0 = (a1 > a0) ? a1 : a0;
      ull m1 = (a3 > a2) ? a3 : a2;
      ull wkA = (m1 > m0) ? m1 : m0;
      int wiA = 4095 - (int)((unsigned)wkA & 0xFFFu);
      if (tid == 0) {
        fps_g[bA * NPT + it] = wiA;
        if (((it + 1) & 63) == 0) {
          __threadfence();
          __hip_atomic_store(&ctl->fps_prog[bA], it, __ATOMIC_RELAXED,
                             __HIP_MEMORY_SCOPE_AGENT);
        }
      }
      float4 cA = sm.f.pts[wiA];          // one ds_read_b128, broadcast
      wxA = cA.x; wyA = cA.y; wzA = cA.z;
      // ---- poll B ----------------------------------------------------------
      for (;;) {
        a0 = __hip_atomic_load(&sm.f.slots[1][par][0], __ATOMIC_RELAXED, __HIP_MEMORY_SCOPE_WORKGROUP);
        a1 = __hip_atomic_load(&sm.f.slots[1][par][1], __ATOMIC_RELAXED, __HIP_MEMORY_SCOPE_WORKGROUP);
        a2 = __hip_atomic_load(&sm.f.slots[1][par][2], __ATOMIC_RELAXED, __HIP_MEMORY_SCOPE_WORKGROUP);
        a3 = __hip_atomic_load(&sm.f.slots[1][par][3], __ATOMIC_RELAXED, __HIP_MEMORY_SCOPE_WORKGROUP);
        if (a0 >= itbase && a1 >= itbase && a2 >= itbase && a3 >= itbase) break;
      }
      m0 = (a1 > a0) ? a1 : a0;
      m1 = (a3 > a2) ? a3 : a2;
      ull wkB = (m1 > m0) ? m1 : m0;
      int wiB = 4095 - (int)((unsigned)wkB & 0xFFFu);
      if (tid == 0) {
        fps_g[bB * NPT + it] = wiB;
        if (((it + 1) & 63) == 0) {
          __threadfence();
          __hip_atomic_store(&ctl->fps_prog[bB], it, __ATOMIC_RELAXED,
                             __HIP_MEMORY_SCOPE_AGENT);
        }
      }
      // B winner coords from global (L2-hot); latency hides under next updateA
      wxB = xg[wiB]; wyB = xg[NQ + wiB]; wzB = xg[2 * NQ + wiB];
    }
    // prog[b]=1023 published inside the loop at it=1023; nothing else to do.
  } else if (bk < 132) {
    // ================= kNN, lazy-queue top-16 (transposed queue) =============
#pragma clang fp contract(off)
    int rel = bk - 4;
    int b = rel >> 4;
    int n0 = (rel & 15) << 8;
    const float* xb = x + (size_t)b * 3 * NQ;
    int n = n0 + tid;
    float qx = xb[n], qy = xb[NQ + n], qz = xb[2 * NQ + n];
    float qw = (qx * qx + qy * qy) + qz * qz;
    float bd[16]; int bi[16];
#pragma unroll
    for (int i = 0; i < 16; i++) { bd[i] = 3.4e38f; bi[i] = -1; }
    float thr = 3.4e38f;
    int cnt = 0;

    auto insert16 = [&](float ed, int em) {
#pragma unroll
      for (int i2 = 15; i2 >= 1; --i2) {
        bool ltp = ed < bd[i2 - 1];
        bool ltc = ed < bd[i2];
        float nv = ltp ? bd[i2 - 1] : ed;
        int ni = ltp ? bi[i2 - 1] : em;
        bd[i2] = ltc ? nv : bd[i2];
        bi[i2] = ltc ? ni : bi[i2];
      }
      bool lt0 = ed < bd[0];
      bd[0] = lt0 ? ed : bd[0];
      bi[0] = lt0 ? em : bi[0];
    };
    auto drain = [&]() {
#pragma unroll 1
      for (int j = 0; j < cnt; j++) {
        unsigned long long e = sm.k.qbuf[j * 256 + tid];   // transposed: ~no conflicts
        float ed = __uint_as_float((unsigned int)(e >> 32));
        int em = (int)(e & 0xFFFFFFFFull);
        if (ed < bd[15]) insert16(ed, em);
      }
      cnt = 0;
      thr = bd[15];
    };

    for (int c0 = 0; c0 < NQ; c0 += 2048) {
      __syncthreads();
      for (int i = tid; i < 2048; i += 256) {
        int g = c0 + i;
        float pxv = xb[g], pyv = xb[NQ + g], pzv = xb[2 * NQ + g];
        float sq = (pxv * pxv + pyv * pyv) + pzv * pzv;
        sm.k.pts[i] = make_float4(pxv, pyv, pzv, sq);
      }
      __syncthreads();
      for (int m0 = 0; m0 < 2048; m0 += 8) {
        float4 p[8];
#pragma unroll
        for (int j = 0; j < 8; j++) p[j] = sm.k.pts[m0 + j];
        float d[8];
#pragma unroll
        for (int j = 0; j < 8; j++) {
          float dot = (qx * p[j].x + qy * p[j].y) + qz * p[j].z;
          d[j] = (qw + p[j].w) - 2.0f * dot;
        }
#pragma unroll
        for (int j = 0; j < 8; j++) {
          if (d[j] < thr) {
            sm.k.qbuf[cnt * 256 + tid] =
                ((unsigned long long)__float_as_uint(d[j]) << 32) |
                (unsigned int)(c0 + m0 + j);
            cnt++;
          }
        }
        if (__ballot(cnt > CAP - 8)) drain();
      }
    }
    drain();

    int4* dst = (int4*)(knn + (((size_t)(b << 12) + n) << 4));
    dst[0] = make_int4(bi[0], bi[1], bi[2], bi[3]);
    dst[1] = make_int4(bi[4], bi[5], bi[6], bi[7]);
    dst[2] = make_int4(bi[8], bi[9], bi[10], bi[11]);
    dst[3] = make_int4(bi[12], bi[13], bi[14], bi[15]);
    __syncthreads();
    if (tid == 0) release_inc(&ctl->knn_done);
  } else if (bk < 260) {
    // ================= f8 (1x1 conv) ========================================
    int rel = bk - 132;
    int t = rel * 256 + tid;
    int b = t >> 12, n = t & 4095;
    const float* fb = f + (size_t)b * 3 * NQ + n;
    float f0 = fb[0], f1 = fb[NQ], f2 = fb[2 * NQ];
    float o8v[8];
#pragma unroll
    for (int o = 0; o < 8; o++) {
      o8v[o] = w_in[o * 3 + 0] * f0 + w_in[o * 3 + 1] * f1 + w_in[o * 3 + 2] * f2 + b_in[o];
    }
    float4* dst = (float4*)(f8t + ((size_t)t << 3));
    dst[0] = make_float4(o8v[0], o8v[1], o8v[2], o8v[3]);
    dst[1] = make_float4(o8v[4], o8v[5], o8v[6], o8v[7]);
    __syncthreads();
    if (tid == 0) release_inc(&ctl->f8_done);
  } else if (bk < 2308) {
    // ================= stats (+ inline finalize in last block) ==============
    if (tid == 0) { spin_ge(&ctl->knn_done, 128); spin_ge(&ctl->f8_done, 128); }
    __syncthreads();
    __threadfence();   // acquire: invalidate L1 before reading knn/f8t
    int rel = bk - 260;
    int b = rel >> 8;
    int n0 = (rel & 255) << 4;
    if (tid < 128) {
#pragma unroll
      for (int c = 0; c < 8; c++) {
        float a = w1[tid * 16 + c];
        sm.g.Alds[tid][c] = a;
        sm.g.Dlds[tid][c] = w1[tid * 16 + 8 + c] - a;
      }
    }
    int nl = tid & 15, kk = tid >> 4;
    int nmy = n0 + nl;
    int idx = knn[(((size_t)(b << 12) + nmy) << 4) + kk];
    const float4* fp4 = (const float4*)(f8t + (((size_t)(b << 12) + idx) << 3));
    float4 v0 = fp4[0], v1 = fp4[1];
    float* dstp = &sm.g.fnb[nl][kk << 3];
    ((float4*)dstp)[0] = v0;
    ((float4*)dstp)[1] = v1;
    if (tid < 16) {
      const float4* fq4 = (const float4*)(f8t + (((size_t)(b << 12) + n0 + tid) << 3));
      float4 a = fq4[0], c4 = fq4[1];
      sm.g.fqb[tid][0] = a.x; sm.g.fqb[tid][1] = a.y; sm.g.fqb[tid][2] = a.z; sm.g.fqb[tid][3] = a.w;
      sm.g.fqb[tid][4] = c4.x; sm.g.fqb[tid][5] = c4.y; sm.g.fqb[tid][6] = c4.z; sm.g.fqb[tid][7] = c4.w;
    }
    __syncthreads();
    int o8 = tid >> 4;
    int obase = o8 << 3;
    float fq[8];
#pragma unroll
    for (int c = 0; c < 8; c++) fq[c] = sm.g.fqb[nl][c];
    float tv[8], Ar[64];
#pragma unroll
    for (int oo = 0; oo < 8; oo++) {
      float acc = 0.f;
#pragma unroll
      for (int c = 0; c < 8; c++) acc += sm.g.Dlds[obase + oo][c] * fq[c];
      tv[oo] = acc;
#pragma unroll
      for (int c = 0; c < 8; c++) Ar[oo * 8 + c] = sm.g.Alds[obase + oo][c];
    }
    float s = 0.f, s2 = 0.f;
    for (int k = 0; k < 16; k++) {
      float4 g0 = *(const float4*)&sm.g.fnb[nl][k * 8];
      float4 g1 = *(const float4*)&sm.g.fnb[nl][k * 8 + 4];
      float fn[8] = {g0.x, g0.y, g0.z, g0.w, g1.x, g1.y, g1.z, g1.w};
#pragma unroll
      for (int oo = 0; oo < 8; oo++) {
        float acc = tv[oo];
#pragma unroll
        for (int c = 0; c < 8; c++) acc += Ar[oo * 8 + c] * fn[c];
        s += acc; s2 += acc * acc;
      }
    }
#pragma unroll
    for (int m = 1; m < 64; m <<= 1) {
      s += __shfl_xor(s, m, 64);
      s2 += __shfl_xor(s2, m, 64);
    }
    if ((tid & 63) == 0) {
      int g = tid >> 6;
      atomicAdd(&stats[((b << 2) + g) * 2 + 0], (double)s);
      atomicAdd(&stats[((b << 2) + g) * 2 + 1], (double)s2);
    }
    __syncthreads();
    if (tid == 0) {
      __threadfence();
      int old = __hip_atomic_fetch_add(&ctl->stats_done, 1, __ATOMIC_ACQ_REL,
                                       __HIP_MEMORY_SCOPE_AGENT);
      sm.g.last = (old == 2047);
    }
    __syncthreads();
    if (sm.g.last) {
      if (tid < 32) {
        unsigned long long r0 = __hip_atomic_load((unsigned long long*)&stats[tid * 2],
                                                  __ATOMIC_RELAXED, __HIP_MEMORY_SCOPE_AGENT);
        unsigned long long r1 = __hip_atomic_load((unsigned long long*)&stats[tid * 2 + 1],
                                                  __ATOMIC_RELAXED, __HIP_MEMORY_SCOPE_AGENT);
        double cnt = 2097152.0;                     // 32 * 4096 * 16
        double mean = __longlong_as_double((long long)r0) / cnt;
        double var = __longlong_as_double((long long)r1) / cnt - mean * mean;
        float rstd = (float)(1.0 / sqrt(var + 1e-5));
        musd[tid * 2] = (float)mean;
        musd[tid * 2 + 1] = rstd;
      }
      __syncthreads();
      if (tid == 0) release_inc(&ctl->fin_done);
    }
  } else if (bk < 2820) {
    // ================= out1: recompute h for selected, GN+leaky+max =========
    int rel = bk - 2308;
    int b = rel >> 6;
    int j0 = (rel & 63) << 4;
    if (tid == 0) {
      spin_ge(&ctl->fps_prog[b], j0 + 15);          // only need fps prefix
      spin_ge(&ctl->fin_done, 1);
    }
    __syncthreads();
    __threadfence();
    float* out1 = out + 24576;
    if (tid < 128) {
#pragma unroll
      for (int c = 0; c < 8; c++) {
        float a = w1[tid * 16 + c];
        sm.g.Alds[tid][c] = a;
        sm.g.Dlds[tid][c] = w1[tid * 16 + 8 + c] - a;
      }
    }
    int nl = tid & 15, kk = tid >> 4;
    int nmy = fps_g[b * NPT + j0 + nl];
    int idx = knn[(((size_t)(b << 12) + nmy) << 4) + kk];
    const float4* fp4 = (const float4*)(f8t + (((size_t)(b << 12) + idx) << 3));
    float4 v0 = fp4[0], v1 = fp4[1];
    float* dstp = &sm.g.fnb[nl][kk << 3];
    ((float4*)dstp)[0] = v0;
    ((float4*)dstp)[1] = v1;
    if (tid < 16) {
      int nq = fps_g[b * NPT + j0 + tid];
      const float4* fq4 = (const float4*)(f8t + (((size_t)(b << 12) + nq) << 3));
      float4 a = fq4[0], c4 = fq4[1];
      sm.g.fqb[tid][0] = a.x; sm.g.fqb[tid][1] = a.y; sm.g.fqb[tid][2] = a.z; sm.g.fqb[tid][3] = a.w;
      sm.g.fqb[tid][4] = c4.x; sm.g.fqb[tid][5] = c4.y; sm.g.fqb[tid][6] = c4.z; sm.g.fqb[tid][7] = c4.w;
    }
    __syncthreads();
    int o8 = tid >> 4;
    int obase = o8 << 3;
    float fq[8];
#pragma unroll
    for (int c = 0; c < 8; c++) fq[c] = sm.g.fqb[nl][c];
    float tv[8], Ar[64];
#pragma unroll
    for (int oo = 0; oo < 8; oo++) {
      float acc = 0.f;
#pragma unroll
      for (int c = 0; c < 8; c++) acc += sm.g.Dlds[obase + oo][c] * fq[c];
      tv[oo] = acc;
#pragma unroll
      for (int c = 0; c < 8; c++) Ar[oo * 8 + c] = sm.g.Alds[obase + oo][c];
    }
    float mx[8], mn[8];
#pragma unroll
    for (int oo = 0; oo < 8; oo++) { mx[oo] = -3.4e38f; mn[oo] = 3.4e38f; }
    for (int k = 0; k < 16; k++) {
      float4 g0 = *(const float4*)&sm.g.fnb[nl][k * 8];
      float4 g1 = *(const float4*)&sm.g.fnb[nl][k * 8 + 4];
      float fn[8] = {g0.x, g0.y, g0.z, g0.w, g1.x, g1.y, g1.z, g1.w};
#pragma unroll
      for (int oo = 0; oo < 8; oo++) {
        float acc = tv[oo];
#pragma unroll
        for (int c = 0; c < 8; c++) acc += Ar[oo * 8 + c] * fn[c];
        mx[oo] = fmaxf(mx[oo], acc);
        mn[oo] = fminf(mn[oo], acc);
      }
    }
    int g = o8 >> 2;
    int j = j0 + nl;
    float mu = musd[((b << 2) + g) * 2];
    float rstd = musd[((b << 2) + g) * 2 + 1];
#pragma unroll
    for (int oo = 0; oo < 8; oo++) {
      int o = obase + oo;
      float w = gnw[o];
      float v = (w >= 0.f) ? mx[oo] : mn[oo];   // leaky∘affine weakly monotone
      float y = (v - mu) * rstd * w + gnb[o];
      y = (y >= 0.f) ? y : 0.2f * y;
      out1[(((size_t)b * 128 + o) << 10) + j] = y;
    }
  } else {
    // ================= gather: coor + fps_idx as float (prefix-gated) =======
    int rel = bk - 2820;
    if (tid == 0) {
      int b0 = rel >> 2, jmax = ((rel & 3) << 8) + 255;  // block spans j0..j0+255
      spin_ge(&ctl->fps_prog[b0], jmax);                 // 255/511/767/1023: all published
    }
    __syncthreads();
    __threadfence();
    int t = rel * 256 + tid;                      // 8192 = B*NPT
    int b = t >> 10, j = t & 1023;
    int i = fps_g[t];
    const float* xb = x + (size_t)b * 3 * NQ;
    out[((size_t)b * 3 + 0) * NPT + j] = xb[i];
    out[((size_t)b * 3 + 1) * NPT + j] = xb[NQ + i];
    out[((size_t)b * 3 + 2) * NPT + j] = xb[2 * NQ + i];
    out[24576 + 1048576 + t] = (float)i;
  }
}

extern "C" void kernel_launch(void* const* d_in, const int* in_sizes, int n_in,
                              void* d_out, int out_size, void* d_ws, size_t ws_size,
                              hipStream_t stream) {
  const float* x    = (const float*)d_in[0];
  const float* f    = (const float*)d_in[1];
  const float* w_in = (const float*)d_in[2];
  const float* b_in = (const float*)d_in[3];
  const float* w1   = (const float*)d_in[4];
  const float* gnw  = (const float*)d_in[5];
  const float* gnb  = (const float*)d_in[6];
  float* out = (float*)d_out;

  char* ws = (char*)d_ws;
  float*  f8t   = (float*)(ws);                               // 1 MB
  int*    knn   = (int*)(ws + (1 << 20));                     // 2 MB
  int*    fps   = (int*)(ws + (3 << 20));                     // 32 KB
  double* stats = (double*)(ws + (3 << 20) + 32768);          // 512 B
  Ctl*    ctl   = (Ctl*)(ws + (3 << 20) + 32768 + 512);       // 64 B
  float*  musd  = (float*)(ws + (3 << 20) + 32768 + 512 + 64);// 256 B

  hipMemsetAsync(stats, 0, 512 + 64, stream);                 // stats + ctl
  mega_kernel<<<2852, 256, 0, stream>>>(x, f, w_in, b_in, w1, gnw, gnb,
                                        f8t, knn, fps, stats, musd, ctl, out);
}

// Round 3
// 868.636 us; speedup vs baseline: 1.8227x; 1.8227x over previous
//
#include <hip/hip_runtime.h>

#define NQ 4096
#define NPT 1024
#define CAP 16

typedef float vf2 __attribute__((ext_vector_type(2)));
typedef unsigned long long ull;

struct KnnSm { float4 pts[2048]; unsigned long long qbuf[CAP * 256]; };   // 64 KB
struct FpsSm { float4 pts[NQ]; ull slots[2][4]; };                        // 64 KB + 64 B
struct GemmSm {
  float fnb[16][132]; float fqb[16][8]; float Alds[128][8]; float Dlds[128][8];
  int last;
};
union FusedSm { KnnSm k; FpsSm f; GemmSm g; };

struct Ctl { int f8_done, knn_done, fps_done, stats_done, fin_done, pad0, pad1, pad2;
             int fps_prog[8]; };   // 64 B, zeroed by memset each launch

__device__ inline void spin_ge(int* p, int target) {
  while (__hip_atomic_load(p, __ATOMIC_RELAXED, __HIP_MEMORY_SCOPE_AGENT) < target)
    __builtin_amdgcn_s_sleep(16);
}
__device__ inline void release_inc(int* p) {
  __threadfence();   // make this block's global writes visible device-wide
  __hip_atomic_fetch_add(p, 1, __ATOMIC_RELAXED, __HIP_MEMORY_SCOPE_AGENT);
}

// 64-bit lexicographic max across the wave via DPP; lane 63 holds the result.
#define DPP64S(key, CTRL)                                                      \
  {                                                                            \
    unsigned slo = (unsigned)__builtin_amdgcn_update_dpp(                      \
        0, (int)(unsigned)(key), CTRL, 0xF, 0xF, true);                        \
    unsigned shi = (unsigned)__builtin_amdgcn_update_dpp(                      \
        0, (int)(unsigned)((key) >> 32), CTRL, 0xF, 0xF, true);                \
    ull sk = ((ull)shi << 32) | slo;                                           \
    key = (sk > key) ? sk : key;                                               \
  }
#define DPP6(key)                                                              \
  DPP64S(key, 0x111) DPP64S(key, 0x112) DPP64S(key, 0x114) DPP64S(key, 0x118)  \
  DPP64S(key, 0x142) DPP64S(key, 0x143)

__global__ __launch_bounds__(256) void mega_kernel(
    const float* __restrict__ x, const float* __restrict__ f,
    const float* __restrict__ w_in, const float* __restrict__ b_in,
    const float* __restrict__ w1, const float* __restrict__ gnw,
    const float* __restrict__ gnb, float* __restrict__ f8t,
    int* __restrict__ knn, int* __restrict__ fps_g, double* __restrict__ stats,
    float* __restrict__ musd, Ctl* __restrict__ ctl, float* __restrict__ out) {
  __shared__ FusedSm sm;
  int tid = threadIdx.x;
  int bk = blockIdx.x;

  if (bk < 8) {
    // ===== FPS: single batch per block (R1 structure), monotone-key poll ====
    // key = [it:10 | dist:32 | inv:12]; poll: slot >= it<<44; max of the 4
    // slots IS the winner key. setprio(1): this is the kernel's critical
    // latency chain — win issue arbitration vs co-resident stats waves.
#pragma clang fp contract(off)
    __builtin_amdgcn_s_setprio(1);
    int b = bk;
    const float* xb = x + (size_t)b * 3 * NQ;
    vf2 px2[8], py2[8], pz2[8], d2[8];
#pragma unroll
    for (int p = 0; p < 8; p++) {
      int i0 = (p << 9) + tid, i1 = i0 + 256;
      float X0 = xb[i0], Y0 = xb[NQ + i0], Z0 = xb[2 * NQ + i0];
      float X1 = xb[i1], Y1 = xb[NQ + i1], Z1 = xb[2 * NQ + i1];
      px2[p] = vf2{X0, X1}; py2[p] = vf2{Y0, Y1}; pz2[p] = vf2{Z0, Z1};
      sm.f.pts[i0] = make_float4(X0, Y0, Z0, 0.f);
      sm.f.pts[i1] = make_float4(X1, Y1, Z1, 0.f);
      d2[p] = vf2{3.4e38f, 3.4e38f};   // sentinel: fminf(BIG, d_p0)==d_p0
    }
    float wx = xb[0], wy = xb[NQ], wz = xb[2 * NQ];   // winner 0 = point 0
    if (tid == 0) fps_g[b * NPT] = 0;
    if (tid < 8) sm.f.slots[tid >> 2][tid & 3] = 0ull; // < any it<<44
    __syncthreads();
    unsigned invbase = (unsigned)(4095 - tid);
    for (int it = 1; it < NPT; it++) {
      ull itbase = (ull)(unsigned)it << 44;
      int par = it & 1;
      // ---- fused min-update + 16-slot argmax (bitwise == verified math) ----
      vf2 wxv = vf2{wx, wx}, wyv = vf2{wy, wy}, wzv = vf2{wz, wz};
      float tvv[8]; int tss[8];
#pragma unroll
      for (int p = 0; p < 8; p++) {
        vf2 dx = px2[p] - wxv, dy = py2[p] - wyv, dz = pz2[p] - wzv;
        vf2 a = dx * dx, bq = dy * dy, cq = dz * dz;
        vf2 d = (a + bq) + cq;                        // ((a+b)+c), no fma
        float nx = fminf(d2[p].x, d.x);
        float ny = fminf(d2[p].y, d.y);
        d2[p].x = nx; d2[p].y = ny;
        bool g = ny > nx;                             // strict >: lower idx wins tie
        tvv[p] = g ? ny : nx;
        tss[p] = g ? (2 * p + 1) : (2 * p);
      }
#pragma unroll
      for (int s = 0; s < 4; s++) {
        bool g = tvv[2 * s + 1] > tvv[2 * s];
        tvv[s] = g ? tvv[2 * s + 1] : tvv[2 * s];
        tss[s] = g ? tss[2 * s + 1] : tss[2 * s];
      }
      ull key;
      {
        bool g0 = tvv[1] > tvv[0];
        float u0 = g0 ? tvv[1] : tvv[0]; int s0p = g0 ? tss[1] : tss[0];
        bool g1 = tvv[3] > tvv[2];
        float u1 = g1 ? tvv[3] : tvv[2]; int s1p = g1 ? tss[3] : tss[2];
        bool gf = u1 > u0;
        float mv = gf ? u1 : u0; int ms = gf ? s1p : s0p;
        key = itbase | ((ull)__float_as_uint(mv) << 12) |
              (ull)(invbase - ((unsigned)ms << 8));
      }
      DPP6(key)
      if ((tid & 63) == 63)
        __hip_atomic_store(&sm.f.slots[par][tid >> 6], key,
                           __ATOMIC_RELAXED, __HIP_MEMORY_SCOPE_WORKGROUP);
      // ---- poll (no barrier; parity double-buffer) -------------------------
      ull a0, a1, a2, a3;
      for (;;) {
        a0 = __hip_atomic_load(&sm.f.slots[par][0], __ATOMIC_RELAXED, __HIP_MEMORY_SCOPE_WORKGROUP);
        a1 = __hip_atomic_load(&sm.f.slots[par][1], __ATOMIC_RELAXED, __HIP_MEMORY_SCOPE_WORKGROUP);
        a2 = __hip_atomic_load(&sm.f.slots[par][2], __ATOMIC_RELAXED, __HIP_MEMORY_SCOPE_WORKGROUP);
        a3 = __hip_atomic_load(&sm.f.slots[par][3], __ATOMIC_RELAXED, __HIP_MEMORY_SCOPE_WORKGROUP);
        if (a0 >= itbase && a1 >= itbase && a2 >= itbase && a3 >= itbase) break;
      }
      ull m0 = (a1 > a0) ? a1 : a0;
      ull m1 = (a3 > a2) ? a3 : a2;
      ull wk = (m1 > m0) ? m1 : m0;
      int wi = 4095 - (int)((unsigned)wk & 0xFFFu);
      float4 c = sm.f.pts[wi];            // one ds_read_b128, uniform broadcast;
      wx = c.x; wy = c.y; wz = c.z;       // issued before the publish branch
      if (tid == 0) {
        fps_g[b * NPT + it] = wi;
        if (((it + 1) & 63) == 0) {       // publish prefix progress
          __threadfence();
          __hip_atomic_store(&ctl->fps_prog[b], it, __ATOMIC_RELAXED,
                             __HIP_MEMORY_SCOPE_AGENT);
        }
      }
    }
    __syncthreads();
    if (tid == 0) release_inc(&ctl->fps_done);
  } else if (bk < 136) {
    // ================= kNN, lazy-queue top-16 (transposed queue) =============
#pragma clang fp contract(off)
    int rel = bk - 8;
    int b = rel >> 4;
    int n0 = (rel & 15) << 8;
    const float* xb = x + (size_t)b * 3 * NQ;
    int n = n0 + tid;
    float qx = xb[n], qy = xb[NQ + n], qz = xb[2 * NQ + n];
    float qw = (qx * qx + qy * qy) + qz * qz;
    float bd[16]; int bi[16];
#pragma unroll
    for (int i = 0; i < 16; i++) { bd[i] = 3.4e38f; bi[i] = -1; }
    float thr = 3.4e38f;
    int cnt = 0;

    auto insert16 = [&](float ed, int em) {
#pragma unroll
      for (int i2 = 15; i2 >= 1; --i2) {
        bool ltp = ed < bd[i2 - 1];
        bool ltc = ed < bd[i2];
        float nv = ltp ? bd[i2 - 1] : ed;
        int ni = ltp ? bi[i2 - 1] : em;
        bd[i2] = ltc ? nv : bd[i2];
        bi[i2] = ltc ? ni : bi[i2];
      }
      bool lt0 = ed < bd[0];
      bd[0] = lt0 ? ed : bd[0];
      bi[0] = lt0 ? em : bi[0];
    };
    auto drain = [&]() {
#pragma unroll 1
      for (int j = 0; j < cnt; j++) {
        unsigned long long e = sm.k.qbuf[j * 256 + tid];   // transposed: ~no conflicts
        float ed = __uint_as_float((unsigned int)(e >> 32));
        int em = (int)(e & 0xFFFFFFFFull);
        if (ed < bd[15]) insert16(ed, em);
      }
      cnt = 0;
      thr = bd[15];
    };

    for (int c0 = 0; c0 < NQ; c0 += 2048) {
      __syncthreads();
      for (int i = tid; i < 2048; i += 256) {
        int g = c0 + i;
        float pxv = xb[g], pyv = xb[NQ + g], pzv = xb[2 * NQ + g];
        float sq = (pxv * pxv + pyv * pyv) + pzv * pzv;
        sm.k.pts[i] = make_float4(pxv, pyv, pzv, sq);
      }
      __syncthreads();
      for (int m0 = 0; m0 < 2048; m0 += 8) {
        float4 p[8];
#pragma unroll
        for (int j = 0; j < 8; j++) p[j] = sm.k.pts[m0 + j];
        float d[8];
#pragma unroll
        for (int j = 0; j < 8; j++) {
          float dot = (qx * p[j].x + qy * p[j].y) + qz * p[j].z;
          d[j] = (qw + p[j].w) - 2.0f * dot;
        }
#pragma unroll
        for (int j = 0; j < 8; j++) {
          if (d[j] < thr) {
            sm.k.qbuf[cnt * 256 + tid] =
                ((unsigned long long)__float_as_uint(d[j]) << 32) |
                (unsigned int)(c0 + m0 + j);
            cnt++;
          }
        }
        if (__ballot(cnt > CAP - 8)) drain();
      }
    }
    drain();

    int4* dst = (int4*)(knn + (((size_t)(b << 12) + n) << 4));
    dst[0] = make_int4(bi[0], bi[1], bi[2], bi[3]);
    dst[1] = make_int4(bi[4], bi[5], bi[6], bi[7]);
    dst[2] = make_int4(bi[8], bi[9], bi[10], bi[11]);
    dst[3] = make_int4(bi[12], bi[13], bi[14], bi[15]);
    __syncthreads();
    if (tid == 0) release_inc(&ctl->knn_done);
  } else if (bk < 264) {
    // ================= f8 (1x1 conv) ========================================
    int rel = bk - 136;
    int t = rel * 256 + tid;
    int b = t >> 12, n = t & 4095;
    const float* fb = f + (size_t)b * 3 * NQ + n;
    float f0 = fb[0], f1 = fb[NQ], f2 = fb[2 * NQ];
    float o8v[8];
#pragma unroll
    for (int o = 0; o < 8; o++) {
      o8v[o] = w_in[o * 3 + 0] * f0 + w_in[o * 3 + 1] * f1 + w_in[o * 3 + 2] * f2 + b_in[o];
    }
    float4* dst = (float4*)(f8t + ((size_t)t << 3));
    dst[0] = make_float4(o8v[0], o8v[1], o8v[2], o8v[3]);
    dst[1] = make_float4(o8v[4], o8v[5], o8v[6], o8v[7]);
    __syncthreads();
    if (tid == 0) release_inc(&ctl->f8_done);
  } else if (bk < 2312) {
    // ================= stats (+ inline finalize in last block) ==============
    if (tid == 0) { spin_ge(&ctl->knn_done, 128); spin_ge(&ctl->f8_done, 128); }
    __syncthreads();
    __threadfence();   // acquire: invalidate L1 before reading knn/f8t
    int rel = bk - 264;
    int b = rel >> 8;
    int n0 = (rel & 255) << 4;
    if (tid < 128) {
#pragma unroll
      for (int c = 0; c < 8; c++) {
        float a = w1[tid * 16 + c];
        sm.g.Alds[tid][c] = a;
        sm.g.Dlds[tid][c] = w1[tid * 16 + 8 + c] - a;
      }
    }
    int nl = tid & 15, kk = tid >> 4;
    int nmy = n0 + nl;
    int idx = knn[(((size_t)(b << 12) + nmy) << 4) + kk];
    const float4* fp4 = (const float4*)(f8t + (((size_t)(b << 12) + idx) << 3));
    float4 v0 = fp4[0], v1 = fp4[1];
    float* dstp = &sm.g.fnb[nl][kk << 3];
    ((float4*)dstp)[0] = v0;
    ((float4*)dstp)[1] = v1;
    if (tid < 16) {
      const float4* fq4 = (const float4*)(f8t + (((size_t)(b << 12) + n0 + tid) << 3));
      float4 a = fq4[0], c4 = fq4[1];
      sm.g.fqb[tid][0] = a.x; sm.g.fqb[tid][1] = a.y; sm.g.fqb[tid][2] = a.z; sm.g.fqb[tid][3] = a.w;
      sm.g.fqb[tid][4] = c4.x; sm.g.fqb[tid][5] = c4.y; sm.g.fqb[tid][6] = c4.z; sm.g.fqb[tid][7] = c4.w;
    }
    __syncthreads();
    int o8 = tid >> 4;
    int obase = o8 << 3;
    float fq[8];
#pragma unroll
    for (int c = 0; c < 8; c++) fq[c] = sm.g.fqb[nl][c];
    float tv[8], Ar[64];
#pragma unroll
    for (int oo = 0; oo < 8; oo++) {
      float acc = 0.f;
#pragma unroll
      for (int c = 0; c < 8; c++) acc += sm.g.Dlds[obase + oo][c] * fq[c];
      tv[oo] = acc;
#pragma unroll
      for (int c = 0; c < 8; c++) Ar[oo * 8 + c] = sm.g.Alds[obase + oo][c];
    }
    float s = 0.f, s2 = 0.f;
    for (int k = 0; k < 16; k++) {
      float4 g0 = *(const float4*)&sm.g.fnb[nl][k * 8];
      float4 g1 = *(const float4*)&sm.g.fnb[nl][k * 8 + 4];
      float fn[8] = {g0.x, g0.y, g0.z, g0.w, g1.x, g1.y, g1.z, g1.w};
#pragma unroll
      for (int oo = 0; oo < 8; oo++) {
        float acc = tv[oo];
#pragma unroll
        for (int c = 0; c < 8; c++) acc += Ar[oo * 8 + c] * fn[c];
        s += acc; s2 += acc * acc;
      }
    }
#pragma unroll
    for (int m = 1; m < 64; m <<= 1) {
      s += __shfl_xor(s, m, 64);
      s2 += __shfl_xor(s2, m, 64);
    }
    if ((tid & 63) == 0) {
      int g = tid >> 6;
      atomicAdd(&stats[((b << 2) + g) * 2 + 0], (double)s);
      atomicAdd(&stats[((b << 2) + g) * 2 + 1], (double)s2);
    }
    __syncthreads();
    if (tid == 0) {
      __threadfence();
      int old = __hip_atomic_fetch_add(&ctl->stats_done, 1, __ATOMIC_ACQ_REL,
                                       __HIP_MEMORY_SCOPE_AGENT);
      sm.g.last = (old == 2047);
    }
    __syncthreads();
    if (sm.g.last) {
      if (tid < 32) {
        unsigned long long r0 = __hip_atomic_load((unsigned long long*)&stats[tid * 2],
                                                  __ATOMIC_RELAXED, __HIP_MEMORY_SCOPE_AGENT);
        unsigned long long r1 = __hip_atomic_load((unsigned long long*)&stats[tid * 2 + 1],
                                                  __ATOMIC_RELAXED, __HIP_MEMORY_SCOPE_AGENT);
        double cnt = 2097152.0;                     // 32 * 4096 * 16
        double mean = __longlong_as_double((long long)r0) / cnt;
        double var = __longlong_as_double((long long)r1) / cnt - mean * mean;
        float rstd = (float)(1.0 / sqrt(var + 1e-5));
        musd[tid * 2] = (float)mean;
        musd[tid * 2 + 1] = rstd;
      }
      __syncthreads();
      if (tid == 0) release_inc(&ctl->fin_done);
    }
  } else if (bk < 2824) {
    // ================= out1: recompute h for selected, GN+leaky+max =========
    int rel = bk - 2312;
    int b = rel >> 6;
    int j0 = (rel & 63) << 4;
    if (tid == 0) {
      spin_ge(&ctl->fps_prog[b], j0 + 15);          // only need fps prefix
      spin_ge(&ctl->fin_done, 1);
    }
    __syncthreads();
    __threadfence();
    float* out1 = out + 24576;
    if (tid < 128) {
#pragma unroll
      for (int c = 0; c < 8; c++) {
        float a = w1[tid * 16 + c];
        sm.g.Alds[tid][c] = a;
        sm.g.Dlds[tid][c] = w1[tid * 16 + 8 + c] - a;
      }
    }
    int nl = tid & 15, kk = tid >> 4;
    int nmy = fps_g[b * NPT + j0 + nl];
    int idx = knn[(((size_t)(b << 12) + nmy) << 4) + kk];
    const float4* fp4 = (const float4*)(f8t + (((size_t)(b << 12) + idx) << 3));
    float4 v0 = fp4[0], v1 = fp4[1];
    float* dstp = &sm.g.fnb[nl][kk << 3];
    ((float4*)dstp)[0] = v0;
    ((float4*)dstp)[1] = v1;
    if (tid < 16) {
      int nq = fps_g[b * NPT + j0 + tid];
      const float4* fq4 = (const float4*)(f8t + (((size_t)(b << 12) + nq) << 3));
      float4 a = fq4[0], c4 = fq4[1];
      sm.g.fqb[tid][0] = a.x; sm.g.fqb[tid][1] = a.y; sm.g.fqb[tid][2] = a.z; sm.g.fqb[tid][3] = a.w;
      sm.g.fqb[tid][4] = c4.x; sm.g.fqb[tid][5] = c4.y; sm.g.fqb[tid][6] = c4.z; sm.g.fqb[tid][7] = c4.w;
    }
    __syncthreads();
    int o8 = tid >> 4;
    int obase = o8 << 3;
    float fq[8];
#pragma unroll
    for (int c = 0; c < 8; c++) fq[c] = sm.g.fqb[nl][c];
    float tv[8], Ar[64];
#pragma unroll
    for (int oo = 0; oo < 8; oo++) {
      float acc = 0.f;
#pragma unroll
      for (int c = 0; c < 8; c++) acc += sm.g.Dlds[obase + oo][c] * fq[c];
      tv[oo] = acc;
#pragma unroll
      for (int c = 0; c < 8; c++) Ar[oo * 8 + c] = sm.g.Alds[obase + oo][c];
    }
    float mx[8], mn[8];
#pragma unroll
    for (int oo = 0; oo < 8; oo++) { mx[oo] = -3.4e38f; mn[oo] = 3.4e38f; }
    for (int k = 0; k < 16; k++) {
      float4 g0 = *(const float4*)&sm.g.fnb[nl][k * 8];
      float4 g1 = *(const float4*)&sm.g.fnb[nl][k * 8 + 4];
      float fn[8] = {g0.x, g0.y, g0.z, g0.w, g1.x, g1.y, g1.z, g1.w};
#pragma unroll
      for (int oo = 0; oo < 8; oo++) {
        float acc = tv[oo];
#pragma unroll
        for (int c = 0; c < 8; c++) acc += Ar[oo * 8 + c] * fn[c];
        mx[oo] = fmaxf(mx[oo], acc);
        mn[oo] = fminf(mn[oo], acc);
      }
    }
    int g = o8 >> 2;
    int j = j0 + nl;
    float mu = musd[((b << 2) + g) * 2];
    float rstd = musd[((b << 2) + g) * 2 + 1];
#pragma unroll
    for (int oo = 0; oo < 8; oo++) {
      int o = obase + oo;
      float w = gnw[o];
      float v = (w >= 0.f) ? mx[oo] : mn[oo];   // leaky∘affine weakly monotone
      float y = (v - mu) * rstd * w + gnb[o];
      y = (y >= 0.f) ? y : 0.2f * y;
      out1[(((size_t)b * 128 + o) << 10) + j] = y;
    }
  } else {
    // ================= gather: coor + fps_idx as float (prefix-gated) =======
    int rel = bk - 2824;
    if (tid == 0) {
      int b0 = rel >> 2, jmax = ((rel & 3) << 8) + 255;  // block spans j0..j0+255
      spin_ge(&ctl->fps_prog[b0], jmax);                 // 255/511/767/1023: all published
    }
    __syncthreads();
    __threadfence();
    int t = rel * 256 + tid;                      // 8192 = B*NPT
    int b = t >> 10, j = t & 1023;
    int i = fps_g[t];
    const float* xb = x + (size_t)b * 3 * NQ;
    out[((size_t)b * 3 + 0) * NPT + j] = xb[i];
    out[((size_t)b * 3 + 1) * NPT + j] = xb[NQ + i];
    out[((size_t)b * 3 + 2) * NPT + j] = xb[2 * NQ + i];
    out[24576 + 1048576 + t] = (float)i;
  }
}

extern "C" void kernel_launch(void* const* d_in, const int* in_sizes, int n_in,
                              void* d_out, int out_size, void* d_ws, size_t ws_size,
                              hipStream_t stream) {
  const float* x    = (const float*)d_in[0];
  const float* f    = (const float*)d_in[1];
  const float* w_in = (const float*)d_in[2];
  const float* b_in = (const float*)d_in[3];
  const float* w1   = (const float*)d_in[4];
  const float* gnw  = (const float*)d_in[5];
  const float* gnb  = (const float*)d_in[6];
  float* out = (float*)d_out;

  char* ws = (char*)d_ws;
  float*  f8t   = (float*)(ws);                               // 1 MB
  int*    knn   = (int*)(ws + (1 << 20));                     // 2 MB
  int*    fps   = (int*)(ws + (3 << 20));                     // 32 KB
  double* stats = (double*)(ws + (3 << 20) + 32768);          // 512 B
  Ctl*    ctl   = (Ctl*)(ws + (3 << 20) + 32768 + 512);       // 64 B
  float*  musd  = (float*)(ws + (3 << 20) + 32768 + 512 + 64);// 256 B

  hipMemsetAsync(stats, 0, 512 + 64, stream);                 // stats + ctl
  mega_kernel<<<2856, 256, 0, stream>>>(x, f, w_in, b_in, w1, gnw, gnb,
                                        f8t, knn, fps, stats, musd, ctl, out);
}

// Round 4
// 846.054 us; speedup vs baseline: 1.8713x; 1.0267x over previous
//
#include <hip/hip_runtime.h>

#define NQ 4096
#define NPT 1024
#define CAP 16

typedef float vf2 __attribute__((ext_vector_type(2)));
typedef unsigned long long ull;

struct KnnSm { float4 pts[2048]; unsigned long long qbuf[CAP * 256]; };   // 64 KB
struct FpsSm { float4 pts[NQ]; ull slots[2][4]; };                        // 64 KB + 64 B
struct GemmSm {
  float fnb[16][132]; float fqb[16][8]; float Alds[128][8]; float Dlds[128][8];
  int last;
};
union FusedSm { KnnSm k; FpsSm f; GemmSm g; };

struct Ctl { int f8_done, knn_done, fps_done, stats_done, fin_done, pad0, pad1, pad2;
             int fps_prog[8]; };   // 64 B, zeroed by memset each launch

__device__ inline void spin_ge(int* p, int target) {
  while (__hip_atomic_load(p, __ATOMIC_RELAXED, __HIP_MEMORY_SCOPE_AGENT) < target)
    __builtin_amdgcn_s_sleep(16);
}
__device__ inline void release_inc(int* p) {
  __threadfence();   // make this block's global writes visible device-wide
  __hip_atomic_fetch_add(p, 1, __ATOMIC_RELAXED, __HIP_MEMORY_SCOPE_AGENT);
}

// 64-bit lexicographic max across the wave via DPP; lane 63 holds the result.
#define DPP64S(key, CTRL)                                                      \
  {                                                                            \
    unsigned slo = (unsigned)__builtin_amdgcn_update_dpp(                      \
        0, (int)(unsigned)(key), CTRL, 0xF, 0xF, true);                        \
    unsigned shi = (unsigned)__builtin_amdgcn_update_dpp(                      \
        0, (int)(unsigned)((key) >> 32), CTRL, 0xF, 0xF, true);                \
    ull sk = ((ull)shi << 32) | slo;                                           \
    key = (sk > key) ? sk : key;                                               \
  }
#define DPP6(key)                                                              \
  DPP64S(key, 0x111) DPP64S(key, 0x112) DPP64S(key, 0x114) DPP64S(key, 0x118)  \
  DPP64S(key, 0x142) DPP64S(key, 0x143)

__global__ __launch_bounds__(256) void mega_kernel(
    const float* __restrict__ x, const float* __restrict__ f,
    const float* __restrict__ w_in, const float* __restrict__ b_in,
    const float* __restrict__ w1, const float* __restrict__ gnw,
    const float* __restrict__ gnb, float* __restrict__ f8t,
    int* __restrict__ knn, int* __restrict__ fps_g, double* __restrict__ stats,
    float* __restrict__ musd, Ctl* __restrict__ ctl, float* __restrict__ out) {
  __shared__ FusedSm sm;
  int tid = threadIdx.x;
  int bk = blockIdx.x;

  if (bk < 8) {
    // ===== FPS: raw-s_barrier exchange (lgkmcnt-only wait — no vmem drain) ==
    // key = [dist:32 | inv:12] per iteration; lane63 of each wave stores its
    // wave-max to slots[par]; s_waitcnt lgkmcnt(0) + s_barrier syncs the LDS
    // stores in hardware (no poll sampling quantization, and unlike
    // __syncthreads no vmcnt drain of tid0's in-flight fps_g global store).
    // Parity double-buffer keeps the single-barrier WAR argument from R0.
#pragma clang fp contract(off)
    __builtin_amdgcn_s_setprio(1);
    int b = bk;
    const float* xb = x + (size_t)b * 3 * NQ;
    vf2 px2[8], py2[8], pz2[8], d2[8];
#pragma unroll
    for (int p = 0; p < 8; p++) {
      int i0 = (p << 9) + tid, i1 = i0 + 256;
      float X0 = xb[i0], Y0 = xb[NQ + i0], Z0 = xb[2 * NQ + i0];
      float X1 = xb[i1], Y1 = xb[NQ + i1], Z1 = xb[2 * NQ + i1];
      px2[p] = vf2{X0, X1}; py2[p] = vf2{Y0, Y1}; pz2[p] = vf2{Z0, Z1};
      sm.f.pts[i0] = make_float4(X0, Y0, Z0, 0.f);
      sm.f.pts[i1] = make_float4(X1, Y1, Z1, 0.f);
      d2[p] = vf2{3.4e38f, 3.4e38f};   // sentinel: fminf(BIG, d_p0)==d_p0
    }
    float wx = xb[0], wy = xb[NQ], wz = xb[2 * NQ];   // winner 0 = point 0
    if (tid == 0) fps_g[b * NPT] = 0;
    __syncthreads();
    unsigned invbase = (unsigned)(4095 - tid);
    for (int it = 1; it < NPT; it++) {
      int par = it & 1;
      // ---- fused min-update + 16-slot argmax (bitwise == verified math) ----
      vf2 wxv = vf2{wx, wx}, wyv = vf2{wy, wy}, wzv = vf2{wz, wz};
      float tvv[8]; int tss[8];
#pragma unroll
      for (int p = 0; p < 8; p++) {
        vf2 dx = px2[p] - wxv, dy = py2[p] - wyv, dz = pz2[p] - wzv;
        vf2 a = dx * dx, bq = dy * dy, cq = dz * dz;
        vf2 d = (a + bq) + cq;                        // ((a+b)+c), no fma
        float nx = fminf(d2[p].x, d.x);
        float ny = fminf(d2[p].y, d.y);
        d2[p].x = nx; d2[p].y = ny;
        bool g = ny > nx;                             // strict >: lower idx wins tie
        tvv[p] = g ? ny : nx;
        tss[p] = g ? (2 * p + 1) : (2 * p);
      }
#pragma unroll
      for (int s = 0; s < 4; s++) {
        bool g = tvv[2 * s + 1] > tvv[2 * s];
        tvv[s] = g ? tvv[2 * s + 1] : tvv[2 * s];
        tss[s] = g ? tss[2 * s + 1] : tss[2 * s];
      }
      ull key;
      {
        bool g0 = tvv[1] > tvv[0];
        float u0 = g0 ? tvv[1] : tvv[0]; int s0p = g0 ? tss[1] : tss[0];
        bool g1 = tvv[3] > tvv[2];
        float u1 = g1 ? tvv[3] : tvv[2]; int s1p = g1 ? tss[3] : tss[2];
        bool gf = u1 > u0;
        float mv = gf ? u1 : u0; int ms = gf ? s1p : s0p;
        key = ((ull)__float_as_uint(mv) << 12) |
              (ull)(invbase - ((unsigned)ms << 8));
      }
      DPP6(key)
      if ((tid & 63) == 63)
        sm.f.slots[par][tid >> 6] = key;              // plain ds_write_b64
      // ---- hardware barrier exchange: LDS-only wait, no vmem drain ---------
      asm volatile("s_waitcnt lgkmcnt(0)" ::: "memory");
      __builtin_amdgcn_s_barrier();
      asm volatile("" ::: "memory");                  // no hoist of reads above
      __builtin_amdgcn_sched_barrier(0);
      ull a0 = sm.f.slots[par][0], a1 = sm.f.slots[par][1];
      ull a2 = sm.f.slots[par][2], a3 = sm.f.slots[par][3];
      ull m0 = (a1 > a0) ? a1 : a0;
      ull m1 = (a3 > a2) ? a3 : a2;
      ull wk = (m1 > m0) ? m1 : m0;
      int wi = 4095 - (int)((unsigned)wk & 0xFFFu);
      float4 c = sm.f.pts[wi];            // one ds_read_b128, uniform broadcast;
      wx = c.x; wy = c.y; wz = c.z;       // issued before the publish branch
      if (tid == 0) {
        fps_g[b * NPT + it] = wi;
        if (((it + 1) & 63) == 0) {       // publish prefix progress
          __threadfence();
          __hip_atomic_store(&ctl->fps_prog[b], it, __ATOMIC_RELAXED,
                             __HIP_MEMORY_SCOPE_AGENT);
        }
      }
    }
    __syncthreads();
    if (tid == 0) release_inc(&ctl->fps_done);
  } else if (bk < 136) {
    // ================= kNN, lazy-queue top-16 (transposed queue) =============
#pragma clang fp contract(off)
    int rel = bk - 8;
    int b = rel >> 4;
    int n0 = (rel & 15) << 8;
    const float* xb = x + (size_t)b * 3 * NQ;
    int n = n0 + tid;
    float qx = xb[n], qy = xb[NQ + n], qz = xb[2 * NQ + n];
    float qw = (qx * qx + qy * qy) + qz * qz;
    float bd[16]; int bi[16];
#pragma unroll
    for (int i = 0; i < 16; i++) { bd[i] = 3.4e38f; bi[i] = -1; }
    float thr = 3.4e38f;
    int cnt = 0;

    auto insert16 = [&](float ed, int em) {
#pragma unroll
      for (int i2 = 15; i2 >= 1; --i2) {
        bool ltp = ed < bd[i2 - 1];
        bool ltc = ed < bd[i2];
        float nv = ltp ? bd[i2 - 1] : ed;
        int ni = ltp ? bi[i2 - 1] : em;
        bd[i2] = ltc ? nv : bd[i2];
        bi[i2] = ltc ? ni : bi[i2];
      }
      bool lt0 = ed < bd[0];
      bd[0] = lt0 ? ed : bd[0];
      bi[0] = lt0 ? em : bi[0];
    };
    auto drain = [&]() {
#pragma unroll 1
      for (int j = 0; j < cnt; j++) {
        unsigned long long e = sm.k.qbuf[j * 256 + tid];   // transposed: ~no conflicts
        float ed = __uint_as_float((unsigned int)(e >> 32));
        int em = (int)(e & 0xFFFFFFFFull);
        if (ed < bd[15]) insert16(ed, em);
      }
      cnt = 0;
      thr = bd[15];
    };

    for (int c0 = 0; c0 < NQ; c0 += 2048) {
      __syncthreads();
      for (int i = tid; i < 2048; i += 256) {
        int g = c0 + i;
        float pxv = xb[g], pyv = xb[NQ + g], pzv = xb[2 * NQ + g];
        float sq = (pxv * pxv + pyv * pyv) + pzv * pzv;
        sm.k.pts[i] = make_float4(pxv, pyv, pzv, sq);
      }
      __syncthreads();
      for (int m0 = 0; m0 < 2048; m0 += 8) {
        float4 p[8];
#pragma unroll
        for (int j = 0; j < 8; j++) p[j] = sm.k.pts[m0 + j];
        float d[8];
#pragma unroll
        for (int j = 0; j < 8; j++) {
          float dot = (qx * p[j].x + qy * p[j].y) + qz * p[j].z;
          d[j] = (qw + p[j].w) - 2.0f * dot;
        }
#pragma unroll
        for (int j = 0; j < 8; j++) {
          if (d[j] < thr) {
            sm.k.qbuf[cnt * 256 + tid] =
                ((unsigned long long)__float_as_uint(d[j]) << 32) |
                (unsigned int)(c0 + m0 + j);
            cnt++;
          }
        }
        if (__ballot(cnt > CAP - 8)) drain();
      }
    }
    drain();

    int4* dst = (int4*)(knn + (((size_t)(b << 12) + n) << 4));
    dst[0] = make_int4(bi[0], bi[1], bi[2], bi[3]);
    dst[1] = make_int4(bi[4], bi[5], bi[6], bi[7]);
    dst[2] = make_int4(bi[8], bi[9], bi[10], bi[11]);
    dst[3] = make_int4(bi[12], bi[13], bi[14], bi[15]);
    __syncthreads();
    if (tid == 0) release_inc(&ctl->knn_done);
  } else if (bk < 264) {
    // ================= f8 (1x1 conv) ========================================
    int rel = bk - 136;
    int t = rel * 256 + tid;
    int b = t >> 12, n = t & 4095;
    const float* fb = f + (size_t)b * 3 * NQ + n;
    float f0 = fb[0], f1 = fb[NQ], f2 = fb[2 * NQ];
    float o8v[8];
#pragma unroll
    for (int o = 0; o < 8; o++) {
      o8v[o] = w_in[o * 3 + 0] * f0 + w_in[o * 3 + 1] * f1 + w_in[o * 3 + 2] * f2 + b_in[o];
    }
    float4* dst = (float4*)(f8t + ((size_t)t << 3));
    dst[0] = make_float4(o8v[0], o8v[1], o8v[2], o8v[3]);
    dst[1] = make_float4(o8v[4], o8v[5], o8v[6], o8v[7]);
    __syncthreads();
    if (tid == 0) release_inc(&ctl->f8_done);
  } else if (bk < 2312) {
    // ================= stats (+ inline finalize in last block) ==============
    if (tid == 0) { spin_ge(&ctl->knn_done, 128); spin_ge(&ctl->f8_done, 128); }
    __syncthreads();
    __threadfence();   // acquire: invalidate L1 before reading knn/f8t
    int rel = bk - 264;
    int b = rel >> 8;
    int n0 = (rel & 255) << 4;
    if (tid < 128) {
#pragma unroll
      for (int c = 0; c < 8; c++) {
        float a = w1[tid * 16 + c];
        sm.g.Alds[tid][c] = a;
        sm.g.Dlds[tid][c] = w1[tid * 16 + 8 + c] - a;
      }
    }
    int nl = tid & 15, kk = tid >> 4;
    int nmy = n0 + nl;
    int idx = knn[(((size_t)(b << 12) + nmy) << 4) + kk];
    const float4* fp4 = (const float4*)(f8t + (((size_t)(b << 12) + idx) << 3));
    float4 v0 = fp4[0], v1 = fp4[1];
    float* dstp = &sm.g.fnb[nl][kk << 3];
    ((float4*)dstp)[0] = v0;
    ((float4*)dstp)[1] = v1;
    if (tid < 16) {
      const float4* fq4 = (const float4*)(f8t + (((size_t)(b << 12) + n0 + tid) << 3));
      float4 a = fq4[0], c4 = fq4[1];
      sm.g.fqb[tid][0] = a.x; sm.g.fqb[tid][1] = a.y; sm.g.fqb[tid][2] = a.z; sm.g.fqb[tid][3] = a.w;
      sm.g.fqb[tid][4] = c4.x; sm.g.fqb[tid][5] = c4.y; sm.g.fqb[tid][6] = c4.z; sm.g.fqb[tid][7] = c4.w;
    }
    __syncthreads();
    int o8 = tid >> 4;
    int obase = o8 << 3;
    float fq[8];
#pragma unroll
    for (int c = 0; c < 8; c++) fq[c] = sm.g.fqb[nl][c];
    float tv[8], Ar[64];
#pragma unroll
    for (int oo = 0; oo < 8; oo++) {
      float acc = 0.f;
#pragma unroll
      for (int c = 0; c < 8; c++) acc += sm.g.Dlds[obase + oo][c] * fq[c];
      tv[oo] = acc;
#pragma unroll
      for (int c = 0; c < 8; c++) Ar[oo * 8 + c] = sm.g.Alds[obase + oo][c];
    }
    float s = 0.f, s2 = 0.f;
    for (int k = 0; k < 16; k++) {
      float4 g0 = *(const float4*)&sm.g.fnb[nl][k * 8];
      float4 g1 = *(const float4*)&sm.g.fnb[nl][k * 8 + 4];
      float fn[8] = {g0.x, g0.y, g0.z, g0.w, g1.x, g1.y, g1.z, g1.w};
#pragma unroll
      for (int oo = 0; oo < 8; oo++) {
        float acc = tv[oo];
#pragma unroll
        for (int c = 0; c < 8; c++) acc += Ar[oo * 8 + c] * fn[c];
        s += acc; s2 += acc * acc;
      }
    }
#pragma unroll
    for (int m = 1; m < 64; m <<= 1) {
      s += __shfl_xor(s, m, 64);
      s2 += __shfl_xor(s2, m, 64);
    }
    if ((tid & 63) == 0) {
      int g = tid >> 6;
      atomicAdd(&stats[((b << 2) + g) * 2 + 0], (double)s);
      atomicAdd(&stats[((b << 2) + g) * 2 + 1], (double)s2);
    }
    __syncthreads();
    if (tid == 0) {
      __threadfence();
      int old = __hip_atomic_fetch_add(&ctl->stats_done, 1, __ATOMIC_ACQ_REL,
                                       __HIP_MEMORY_SCOPE_AGENT);
      sm.g.last = (old == 2047);
    }
    __syncthreads();
    if (sm.g.last) {
      if (tid < 32) {
        unsigned long long r0 = __hip_atomic_load((unsigned long long*)&stats[tid * 2],
                                                  __ATOMIC_RELAXED, __HIP_MEMORY_SCOPE_AGENT);
        unsigned long long r1 = __hip_atomic_load((unsigned long long*)&stats[tid * 2 + 1],
                                                  __ATOMIC_RELAXED, __HIP_MEMORY_SCOPE_AGENT);
        double cnt = 2097152.0;                     // 32 * 4096 * 16
        double mean = __longlong_as_double((long long)r0) / cnt;
        double var = __longlong_as_double((long long)r1) / cnt - mean * mean;
        float rstd = (float)(1.0 / sqrt(var + 1e-5));
        musd[tid * 2] = (float)mean;
        musd[tid * 2 + 1] = rstd;
      }
      __syncthreads();
      if (tid == 0) release_inc(&ctl->fin_done);
    }
  } else if (bk < 2824) {
    // ================= out1: recompute h for selected, GN+leaky+max =========
    int rel = bk - 2312;
    int b = rel >> 6;
    int j0 = (rel & 63) << 4;
    if (tid == 0) {
      spin_ge(&ctl->fps_prog[b], j0 + 15);          // only need fps prefix
      spin_ge(&ctl->fin_done, 1);
    }
    __syncthreads();
    __threadfence();
    float* out1 = out + 24576;
    if (tid < 128) {
#pragma unroll
      for (int c = 0; c < 8; c++) {
        float a = w1[tid * 16 + c];
        sm.g.Alds[tid][c] = a;
        sm.g.Dlds[tid][c] = w1[tid * 16 + 8 + c] - a;
      }
    }
    int nl = tid & 15, kk = tid >> 4;
    int nmy = fps_g[b * NPT + j0 + nl];
    int idx = knn[(((size_t)(b << 12) + nmy) << 4) + kk];
    const float4* fp4 = (const float4*)(f8t + (((size_t)(b << 12) + idx) << 3));
    float4 v0 = fp4[0], v1 = fp4[1];
    float* dstp = &sm.g.fnb[nl][kk << 3];
    ((float4*)dstp)[0] = v0;
    ((float4*)dstp)[1] = v1;
    if (tid < 16) {
      int nq = fps_g[b * NPT + j0 + tid];
      const float4* fq4 = (const float4*)(f8t + (((size_t)(b << 12) + nq) << 3));
      float4 a = fq4[0], c4 = fq4[1];
      sm.g.fqb[tid][0] = a.x; sm.g.fqb[tid][1] = a.y; sm.g.fqb[tid][2] = a.z; sm.g.fqb[tid][3] = a.w;
      sm.g.fqb[tid][4] = c4.x; sm.g.fqb[tid][5] = c4.y; sm.g.fqb[tid][6] = c4.z; sm.g.fqb[tid][7] = c4.w;
    }
    __syncthreads();
    int o8 = tid >> 4;
    int obase = o8 << 3;
    float fq[8];
#pragma unroll
    for (int c = 0; c < 8; c++) fq[c] = sm.g.fqb[nl][c];
    float tv[8], Ar[64];
#pragma unroll
    for (int oo = 0; oo < 8; oo++) {
      float acc = 0.f;
#pragma unroll
      for (int c = 0; c < 8; c++) acc += sm.g.Dlds[obase + oo][c] * fq[c];
      tv[oo] = acc;
#pragma unroll
      for (int c = 0; c < 8; c++) Ar[oo * 8 + c] = sm.g.Alds[obase + oo][c];
    }
    float mx[8], mn[8];
#pragma unroll
    for (int oo = 0; oo < 8; oo++) { mx[oo] = -3.4e38f; mn[oo] = 3.4e38f; }
    for (int k = 0; k < 16; k++) {
      float4 g0 = *(const float4*)&sm.g.fnb[nl][k * 8];
      float4 g1 = *(const float4*)&sm.g.fnb[nl][k * 8 + 4];
      float fn[8] = {g0.x, g0.y, g0.z, g0.w, g1.x, g1.y, g1.z, g1.w};
#pragma unroll
      for (int oo = 0; oo < 8; oo++) {
        float acc = tv[oo];
#pragma unroll
        for (int c = 0; c < 8; c++) acc += Ar[oo * 8 + c] * fn[c];
        mx[oo] = fmaxf(mx[oo], acc);
        mn[oo] = fminf(mn[oo], acc);
      }
    }
    int g = o8 >> 2;
    int j = j0 + nl;
    float mu = musd[((b << 2) + g) * 2];
    float rstd = musd[((b << 2) + g) * 2 + 1];
#pragma unroll
    for (int oo = 0; oo < 8; oo++) {
      int o = obase + oo;
      float w = gnw[o];
      float v = (w >= 0.f) ? mx[oo] : mn[oo];   // leaky∘affine weakly monotone
      float y = (v - mu) * rstd * w + gnb[o];
      y = (y >= 0.f) ? y : 0.2f * y;
      out1[(((size_t)b * 128 + o) << 10) + j] = y;
    }
  } else {
    // ================= gather: coor + fps_idx as float (prefix-gated) =======
    int rel = bk - 2824;
    if (tid == 0) {
      int b0 = rel >> 2, jmax = ((rel & 3) << 8) + 255;  // block spans j0..j0+255
      spin_ge(&ctl->fps_prog[b0], jmax);                 // 255/511/767/1023: all published
    }
    __syncthreads();
    __threadfence();
    int t = rel * 256 + tid;                      // 8192 = B*NPT
    int b = t >> 10, j = t & 1023;
    int i = fps_g[t];
    const float* xb = x + (size_t)b * 3 * NQ;
    out[((size_t)b * 3 + 0) * NPT + j] = xb[i];
    out[((size_t)b * 3 + 1) * NPT + j] = xb[NQ + i];
    out[((size_t)b * 3 + 2) * NPT + j] = xb[2 * NQ + i];
    out[24576 + 1048576 + t] = (float)i;
  }
}

extern "C" void kernel_launch(void* const* d_in, const int* in_sizes, int n_in,
                              void* d_out, int out_size, void* d_ws, size_t ws_size,
                              hipStream_t stream) {
  const float* x    = (const float*)d_in[0];
  const float* f    = (const float*)d_in[1];
  const float* w_in = (const float*)d_in[2];
  const float* b_in = (const float*)d_in[3];
  const float* w1   = (const float*)d_in[4];
  const float* gnw  = (const float*)d_in[5];
  const float* gnb  = (const float*)d_in[6];
  float* out = (float*)d_out;

  char* ws = (char*)d_ws;
  float*  f8t   = (float*)(ws);                               // 1 MB
  int*    knn   = (int*)(ws + (1 << 20));                     // 2 MB
  int*    fps   = (int*)(ws + (3 << 20));                     // 32 KB
  double* stats = (double*)(ws + (3 << 20) + 32768);          // 512 B
  Ctl*    ctl   = (Ctl*)(ws + (3 << 20) + 32768 + 512);       // 64 B
  float*  musd  = (float*)(ws + (3 << 20) + 32768 + 512 + 64);// 256 B

  hipMemsetAsync(stats, 0, 512 + 64, stream);                 // stats + ctl
  mega_kernel<<<2856, 256, 0, stream>>>(x, f, w_in, b_in, w1, gnw, gnb,
                                        f8t, knn, fps, stats, musd, ctl, out);
}